// Round 9
// baseline (2787.917 us; speedup 1.0000x reference)
//
#include <hip/hip_runtime.h>
#include <hip/hip_fp16.h>

#define N_ROWS 100000
#define NNODES 150000
#define D 32
#define NEDGE 5000000
#define BINSHIFT 7
#define BINSZ 128                          // nodes per bin
#define NBINS 1172                         // ceil(150000 / 128)
#define NBLK 512                           // scatter/count blocks
#define SCT 1024                           // threads per scatter/count block
#define CPB ((NEDGE + NBLK - 1) / NBLK)    // 9766 edges per block
#define NCOUNTS (NBINS * NBLK)             // 600064
#define SCAN_ITEMS 1024
#define NSCAN (NCOUNTS / SCAN_ITEMS)       // 586 (exact)

// ---------------- stage 1: per-(block,bin) counts matrix (no global atomics) ----------------

__global__ void count_kernel(const int* __restrict__ dst, int* __restrict__ counts) {
    __shared__ int h[NBINS];
    const int t = threadIdx.x;
    for (int b = t; b < NBINS; b += SCT) h[b] = 0;
    __syncthreads();
    const int e0 = blockIdx.x * CPB;
    const int e1 = min(e0 + CPB, NEDGE);
    for (int i = e0 + t; i < e1; i += SCT) atomicAdd(&h[dst[i] >> BINSHIFT], 1);
    __syncthreads();
    for (int b = t; b < NBINS; b += SCT) counts[b * NBLK + blockIdx.x] = h[b];
}

// ---------------- stage 2: device-wide exclusive scan of counts ----------------

__global__ void scanA(const int* __restrict__ counts, int* __restrict__ partials) {
    __shared__ int s[256];
    const int t = threadIdx.x;
    const int base = blockIdx.x * SCAN_ITEMS + t * 4;
    int sum = 0;
#pragma unroll
    for (int k = 0; k < 4; ++k) sum += counts[base + k];
    s[t] = sum;
    __syncthreads();
    for (int off = 128; off > 0; off >>= 1) {
        if (t < off) s[t] += s[t + off];
        __syncthreads();
    }
    if (t == 0) partials[blockIdx.x] = s[0];
}

__global__ void scanB(int* __restrict__ partials) {
    __shared__ int s[256];
    __shared__ int carry;
    const int t = threadIdx.x;
    if (t == 0) carry = 0;
    __syncthreads();
    for (int c = 0; c < (NSCAN + 255) / 256; ++c) {
        int idx = c * 256 + t;
        int v = (idx < NSCAN) ? partials[idx] : 0;
        s[t] = v;
        __syncthreads();
        for (int off = 1; off < 256; off <<= 1) {
            int tmp = (t >= off) ? s[t - off] : 0;
            __syncthreads();
            s[t] += tmp;
            __syncthreads();
        }
        if (idx < NSCAN) partials[idx] = carry + s[t] - v;  // exclusive
        __syncthreads();
        if (t == 0) carry += s[255];
        __syncthreads();
    }
}

__global__ void scanC(const int* __restrict__ counts, const int* __restrict__ partials,
                      int* __restrict__ bases, int* __restrict__ binPtr) {
    __shared__ int s[256];
    const int t = threadIdx.x;
    const int base = blockIdx.x * SCAN_ITEMS + t * 4;
    int c[4];
    int sum = 0;
#pragma unroll
    for (int k = 0; k < 4; ++k) { c[k] = counts[base + k]; sum += c[k]; }
    s[t] = sum;
    __syncthreads();
    for (int off = 1; off < 256; off <<= 1) {
        int v = (t >= off) ? s[t - off] : 0;
        __syncthreads();
        s[t] += v;
        __syncthreads();
    }
    int run = partials[blockIdx.x] + ((t == 0) ? 0 : s[t - 1]);
#pragma unroll
    for (int k = 0; k < 4; ++k) {
        int idx = base + k;
        bases[idx] = run;
        if ((idx & (NBLK - 1)) == 0) binPtr[idx / NBLK] = run;
        run += c[k];
    }
    if (blockIdx.x == 0 && t == 0) binPtr[NBINS] = NEDGE;
}

// ---------------- stage 3: LDS-staged scatter — bin-sorted, piecewise-coalesced stores ----------------

__global__ void __launch_bounds__(SCT, 2)
scatter3(const int* __restrict__ src, const int* __restrict__ dst,
         const int* __restrict__ bases, unsigned int* __restrict__ binned) {
    __shared__ int cnt[NBINS];          // counts, then cursor
    __shared__ int lb[NBINS + 1];       // local exclusive prefix
    __shared__ int gb[NBINS];           // global base per bin for this block
    __shared__ int ssum[SCT];
    __shared__ unsigned int staged[CPB];

    const int t = threadIdx.x;
    const int e0 = blockIdx.x * CPB;
    const int e1 = min(e0 + CPB, NEDGE);
    const int n = e1 - e0;

    for (int b = t; b < NBINS; b += SCT) {
        cnt[b] = 0;
        gb[b] = bases[b * NBLK + blockIdx.x];
    }
    __syncthreads();
    for (int i = e0 + t; i < e1; i += SCT) atomicAdd(&cnt[dst[i] >> BINSHIFT], 1);
    __syncthreads();

    const int i0 = 2 * t, i1 = 2 * t + 1;
    const int c0 = (i0 < NBINS) ? cnt[i0] : 0;
    const int c1 = (i1 < NBINS) ? cnt[i1] : 0;
    ssum[t] = c0 + c1;
    __syncthreads();
    for (int off = 1; off < SCT; off <<= 1) {
        int v = (t >= off) ? ssum[t - off] : 0;
        __syncthreads();
        ssum[t] += v;
        __syncthreads();
    }
    const int excl = (t == 0) ? 0 : ssum[t - 1];
    if (i0 < NBINS) lb[i0] = excl;
    if (i1 < NBINS) lb[i1] = excl + c0;
    if (t == 0) lb[NBINS] = n;
    __syncthreads();

    for (int b = t; b < NBINS; b += SCT) cnt[b] = lb[b];
    __syncthreads();
    for (int i = e0 + t; i < e1; i += SCT) {
        const int dv = dst[i];
        const int bn = dv >> BINSHIFT;
        const int slot = atomicAdd(&cnt[bn], 1);
        staged[slot] = ((unsigned)(dv & (BINSZ - 1)) << 18) | (unsigned)src[i];
    }
    __syncthreads();

    for (int s2 = t; s2 < n; s2 += SCT) {
        int lo = 0, hi = NBINS;
        while (hi - lo > 1) {
            const int mid = (lo + hi) >> 1;
            if (lb[mid] <= s2) lo = mid; else hi = mid;
        }
        binned[gb[lo] + (s2 - lb[lo])] = staged[s2];
    }
}

// ---------------- layer 0 linear: embeddings -> H0 (fp16) ----------------

__global__ void linear0(const float* __restrict__ xa, const float* __restrict__ xb,
                        const float* __restrict__ W, const float* __restrict__ b,
                        __half* __restrict__ H) {
    __shared__ float Wt[D * D];
    __shared__ float bs[D];
    const int tid = threadIdx.x;
    for (int t = tid; t < D * D; t += blockDim.x) {
        int j = t / D, k = t % D;
        Wt[k * D + j] = W[j * D + k];
    }
    if (tid < D) bs[tid] = b[tid];
    __syncthreads();

    const int row = blockIdx.x * 8 + (tid >> 5);
    const int j = tid & 31;

    float xv = (row < N_ROWS) ? xa[row * D + j] : xb[(row - N_ROWS) * D + j];

    float acc = bs[j];
#pragma unroll
    for (int k = 0; k < D; ++k) {
        float a = __shfl(xv, k, D);
        acc = fmaf(a, Wt[k * D + j], acc);
    }
    H[row * D + j] = __float2half(acc);
}

// ---------------- fused agg (LDS accumulator) + ReLU + optional next linear ----------------
// One block per bin, 1024 threads (32 groups of 32 lanes), edge-parallel.
// MODE 0: epilogue = relu + linear(W,b) -> Hout fp16  (LDS-broadcast reads, no shfl)
// MODE 1: epilogue = relu -> out f32
template <int MODE>
__global__ void __launch_bounds__(1024, 2)
agg_lds2(const int* __restrict__ binPtr, const unsigned int* __restrict__ binned,
         const __half* __restrict__ Hin, const float* __restrict__ W,
         const float* __restrict__ b, __half* __restrict__ Hout, float* __restrict__ out) {
    __shared__ float acc[BINSZ * D];  // 16 KB
    __shared__ float Wt[D * D];
    __shared__ float bs[D];

    const int t = threadIdx.x;
    const int g = t >> 5;   // 32 groups
    const int j = t & 31;
    const int bin = blockIdx.x;
    const int nodeBase = bin << BINSHIFT;
    const int nNodes = min(BINSZ, NNODES - nodeBase);

    if (MODE == 0) {
        for (int x = t; x < D * D; x += 1024) {
            int jj = x / D, kk = x % D;
            Wt[kk * D + jj] = W[jj * D + kk];
        }
        if (t < D) bs[t] = b[t];
    }
    // self-loop init (real rows only; ghost rows never touched)
    for (int r = g; r < nNodes; r += 32)
        acc[r * D + j] = __half2float(Hin[(nodeBase + r) * D + j]);
    __syncthreads();

    const int e0 = binPtr[bin];
    const int nE = binPtr[bin + 1] - e0;
    const int nTile = nE & ~127;  // full tiles of 128 edges (32 groups x 4)

    for (int base = g * 4; base < nTile; base += 128) {
        const int e = e0 + base;
        const unsigned u0 = binned[e];
        const unsigned u1 = binned[e + 1];
        const unsigned u2 = binned[e + 2];
        const unsigned u3 = binned[e + 3];
        const float v0 = __half2float(Hin[(u0 & 0x3FFFFu) * D + j]);
        const float v1 = __half2float(Hin[(u1 & 0x3FFFFu) * D + j]);
        const float v2 = __half2float(Hin[(u2 & 0x3FFFFu) * D + j]);
        const float v3 = __half2float(Hin[(u3 & 0x3FFFFu) * D + j]);
        atomicAdd(&acc[(u0 >> 18) * D + j], v0);
        atomicAdd(&acc[(u1 >> 18) * D + j], v1);
        atomicAdd(&acc[(u2 >> 18) * D + j], v2);
        atomicAdd(&acc[(u3 >> 18) * D + j], v3);
    }
    for (int k = nTile + g; k < nE; k += 32) {
        const unsigned u = binned[e0 + k];
        const float v = __half2float(Hin[(u & 0x3FFFFu) * D + j]);
        atomicAdd(&acc[(u >> 18) * D + j], v);
    }
    __syncthreads();

    if (MODE == 1) {
        for (int r = g; r < nNodes; r += 32)
            out[(nodeBase + r) * D + j] = fmaxf(acc[r * D + j], 0.0f);
    } else {
        // x = relu(acc[r][*]); Hout[r][j] = fp16(bs[j] + sum_k x[k] * Wt[k][j])
        for (int r = g; r < nNodes; r += 32) {
            float nacc = bs[j];
#pragma unroll
            for (int k = 0; k < D; ++k) {
                const float x = fmaxf(acc[r * D + k], 0.0f);  // LDS broadcast read
                nacc = fmaf(x, Wt[k * D + j], nacc);
            }
            Hout[(nodeBase + r) * D + j] = __float2half(nacc);
        }
    }
}

// ---------------- launch ----------------

extern "C" void kernel_launch(void* const* d_in, const int* in_sizes, int n_in,
                              void* d_out, int out_size, void* d_ws, size_t ws_size,
                              hipStream_t stream) {
    const float* row_embed = (const float*)d_in[0];
    const float* col_embed = (const float*)d_in[1];
    const float* W0 = (const float*)d_in[2];
    const float* b0 = (const float*)d_in[3];
    const float* W1 = (const float*)d_in[4];
    const float* b1 = (const float*)d_in[5];
    const float* W2 = (const float*)d_in[6];
    const float* b2 = (const float*)d_in[7];
    const int* ei = (const int*)d_in[8];
    const int* src = ei;
    const int* dst = ei + NEDGE;
    float* out = (float*)d_out;

    // workspace carve-up (~44 MB)
    __half* H0 = (__half*)d_ws;                                       // 9.6 MB
    __half* H1 = H0 + (size_t)NNODES * D;                             // 9.6 MB
    unsigned int* binned = (unsigned int*)(H1 + (size_t)NNODES * D);  // 20 MB
    int* counts = (int*)(binned + NEDGE);                             // 2.4 MB
    int* bases = counts + NCOUNTS;                                    // 2.4 MB
    int* partials = bases + NCOUNTS;                                  // 586
    int* binPtr = partials + NSCAN;                                   // NBINS+1

    const int row_grid = NNODES / 8;  // 18750 exact

    // bin-level CSR build — atomic-free counting sort (rebuilt every call; stateless)
    count_kernel<<<NBLK, SCT, 0, stream>>>(dst, counts);
    scanA<<<NSCAN, 256, 0, stream>>>(counts, partials);
    scanB<<<1, 256, 0, stream>>>(partials);
    scanC<<<NSCAN, 256, 0, stream>>>(counts, partials, bases, binPtr);
    scatter3<<<NBLK, SCT, 0, stream>>>(src, dst, bases, binned);

    // layer chain: linear0, then 3 fused agg(+linear) kernels
    linear0<<<row_grid, 256, 0, stream>>>(row_embed, col_embed, W0, b0, H0);
    agg_lds2<0><<<NBINS, 1024, 0, stream>>>(binPtr, binned, H0, W1, b1, H1, nullptr);
    agg_lds2<0><<<NBINS, 1024, 0, stream>>>(binPtr, binned, H1, W2, b2, H0, nullptr);
    agg_lds2<1><<<NBINS, 1024, 0, stream>>>(binPtr, binned, H0, nullptr, nullptr, nullptr, out);

    (void)in_sizes; (void)n_in; (void)out_size; (void)ws_size;
}

// Round 10
// 492.509 us; speedup vs baseline: 5.6606x; 5.6606x over previous
//
#include <hip/hip_runtime.h>
#include <hip/hip_fp16.h>

#define N_ROWS 100000
#define NNODES 150000
#define D 32
#define NEDGE 5000000
#define BINSHIFT 7
#define BINSZ 128                          // nodes per bin
#define NBINS 1172                         // ceil(150000 / 128)
#define NBLK 512                           // scatter/count blocks
#define SCT 1024                           // threads per scatter/count block
#define CPB ((NEDGE + NBLK - 1) / NBLK)    // 9766 edges per block
#define NCOUNTS (NBINS * NBLK)             // 600064
#define SCAN_ITEMS 1024
#define NSCAN (NCOUNTS / SCAN_ITEMS)       // 586 (exact)

// ---------------- stage 1: per-(block,bin) counts matrix (no global atomics) ----------------
// 4 wave-interleaved sub-histograms cut LDS-atomic contention ~4x.

__global__ void count_kernel(const int* __restrict__ dst, int* __restrict__ counts) {
    __shared__ int h[4 * NBINS];
    const int t = threadIdx.x;
    const int sub = ((t >> 6) & 3) * NBINS;
    for (int b = t; b < 4 * NBINS; b += SCT) h[b] = 0;
    __syncthreads();
    const int e0 = blockIdx.x * CPB;
    const int e1 = min(e0 + CPB, NEDGE);
    for (int i = e0 + t; i < e1; i += SCT) atomicAdd(&h[sub + (dst[i] >> BINSHIFT)], 1);
    __syncthreads();
    for (int b = t; b < NBINS; b += SCT)
        counts[b * NBLK + blockIdx.x] = h[b] + h[NBINS + b] + h[2 * NBINS + b] + h[3 * NBINS + b];
}

// ---------------- stage 2: device-wide exclusive scan of counts ----------------

__global__ void scanA(const int* __restrict__ counts, int* __restrict__ partials) {
    __shared__ int s[256];
    const int t = threadIdx.x;
    const int base = blockIdx.x * SCAN_ITEMS + t * 4;
    int sum = 0;
#pragma unroll
    for (int k = 0; k < 4; ++k) sum += counts[base + k];
    s[t] = sum;
    __syncthreads();
    for (int off = 128; off > 0; off >>= 1) {
        if (t < off) s[t] += s[t + off];
        __syncthreads();
    }
    if (t == 0) partials[blockIdx.x] = s[0];
}

__global__ void scanB(int* __restrict__ partials) {
    __shared__ int s[256];
    __shared__ int carry;
    const int t = threadIdx.x;
    if (t == 0) carry = 0;
    __syncthreads();
    for (int c = 0; c < (NSCAN + 255) / 256; ++c) {
        int idx = c * 256 + t;
        int v = (idx < NSCAN) ? partials[idx] : 0;
        s[t] = v;
        __syncthreads();
        for (int off = 1; off < 256; off <<= 1) {
            int tmp = (t >= off) ? s[t - off] : 0;
            __syncthreads();
            s[t] += tmp;
            __syncthreads();
        }
        if (idx < NSCAN) partials[idx] = carry + s[t] - v;  // exclusive
        __syncthreads();
        if (t == 0) carry += s[255];
        __syncthreads();
    }
}

__global__ void scanC(const int* __restrict__ counts, const int* __restrict__ partials,
                      int* __restrict__ bases, int* __restrict__ binPtr) {
    __shared__ int s[256];
    const int t = threadIdx.x;
    const int base = blockIdx.x * SCAN_ITEMS + t * 4;
    int c[4];
    int sum = 0;
#pragma unroll
    for (int k = 0; k < 4; ++k) { c[k] = counts[base + k]; sum += c[k]; }
    s[t] = sum;
    __syncthreads();
    for (int off = 1; off < 256; off <<= 1) {
        int v = (t >= off) ? s[t - off] : 0;
        __syncthreads();
        s[t] += v;
        __syncthreads();
    }
    int run = partials[blockIdx.x] + ((t == 0) ? 0 : s[t - 1]);
#pragma unroll
    for (int k = 0; k < 4; ++k) {
        int idx = base + k;
        bases[idx] = run;
        if ((idx & (NBLK - 1)) == 0) binPtr[idx / NBLK] = run;
        run += c[k];
    }
    if (blockIdx.x == 0 && t == 0) binPtr[NBINS] = NEDGE;
}

// ---------------- stage 3: LDS-staged scatter — bin-sorted, piecewise-coalesced stores ----------------

__global__ void __launch_bounds__(SCT, 2)
scatter3(const int* __restrict__ src, const int* __restrict__ dst,
         const int* __restrict__ bases, unsigned int* __restrict__ binned) {
    __shared__ int cnt[NBINS];          // counts, then cursor
    __shared__ int lb[NBINS + 1];       // local exclusive prefix
    __shared__ int gb[NBINS];           // global base per bin for this block
    __shared__ int ssum[SCT];
    __shared__ unsigned int staged[CPB];

    const int t = threadIdx.x;
    const int e0 = blockIdx.x * CPB;
    const int e1 = min(e0 + CPB, NEDGE);
    const int n = e1 - e0;

    for (int b = t; b < NBINS; b += SCT) {
        cnt[b] = 0;
        gb[b] = bases[b * NBLK + blockIdx.x];
    }
    __syncthreads();
    for (int i = e0 + t; i < e1; i += SCT) atomicAdd(&cnt[dst[i] >> BINSHIFT], 1);
    __syncthreads();

    const int i0 = 2 * t, i1 = 2 * t + 1;
    const int c0 = (i0 < NBINS) ? cnt[i0] : 0;
    const int c1 = (i1 < NBINS) ? cnt[i1] : 0;
    ssum[t] = c0 + c1;
    __syncthreads();
    for (int off = 1; off < SCT; off <<= 1) {
        int v = (t >= off) ? ssum[t - off] : 0;
        __syncthreads();
        ssum[t] += v;
        __syncthreads();
    }
    const int excl = (t == 0) ? 0 : ssum[t - 1];
    if (i0 < NBINS) lb[i0] = excl;
    if (i1 < NBINS) lb[i1] = excl + c0;
    if (t == 0) lb[NBINS] = n;
    __syncthreads();

    for (int b = t; b < NBINS; b += SCT) cnt[b] = lb[b];
    __syncthreads();
    for (int i = e0 + t; i < e1; i += SCT) {
        const int dv = dst[i];
        const int bn = dv >> BINSHIFT;
        const int slot = atomicAdd(&cnt[bn], 1);
        staged[slot] = ((unsigned)(dv & (BINSZ - 1)) << 18) | (unsigned)src[i];
    }
    __syncthreads();

    for (int s2 = t; s2 < n; s2 += SCT) {
        int lo = 0, hi = NBINS;
        while (hi - lo > 1) {
            const int mid = (lo + hi) >> 1;
            if (lb[mid] <= s2) lo = mid; else hi = mid;
        }
        binned[gb[lo] + (s2 - lb[lo])] = staged[s2];
    }
}

// ---------------- stage 4: per-bin fine counting sort -> full CSR by dst ----------------
// 1024 threads, per-wave private histograms: LDS atomics contend only within a wave.

__global__ void fine_sort(const int* __restrict__ binPtr, const unsigned int* __restrict__ binned,
                          int* __restrict__ rowptr, int* __restrict__ srcSorted) {
    __shared__ int hist[16 * BINSZ];   // [wave][row] 8 KB
    __shared__ int cnt[BINSZ];
    __shared__ int rowStart[BINSZ];
    const int t = threadIdx.x;
    const int w = t >> 6;
    const int bin = blockIdx.x;
    const int nodeBase = bin << BINSHIFT;
    const int nNodes = min(BINSZ, NNODES - nodeBase);
    const int e0 = binPtr[bin];
    const int e1 = binPtr[bin + 1];

    for (int i = t; i < 16 * BINSZ; i += 1024) hist[i] = 0;
    __syncthreads();
    for (int e = e0 + t; e < e1; e += 1024)
        atomicAdd(&hist[(w << 7) | (binned[e] >> 18)], 1);
    __syncthreads();
    // column pass: wave-exclusive offsets + per-row totals
    if (t < BINSZ) {
        int run = 0;
        for (int w2 = 0; w2 < 16; ++w2) {
            const int c = hist[(w2 << 7) | t];
            hist[(w2 << 7) | t] = run;
            run += c;
        }
        cnt[t] = run;
        rowStart[t] = run;
    }
    __syncthreads();
    // inclusive scan over rows
    for (int off = 1; off < BINSZ; off <<= 1) {
        int v = 0;
        if (t < BINSZ && t >= off) v = rowStart[t - off];
        __syncthreads();
        if (t < BINSZ) rowStart[t] += v;
        __syncthreads();
    }
    if (t < nNodes) rowptr[nodeBase + t] = e0 + rowStart[t] - cnt[t];
    // fold row-exclusive base into each wave's offset
    for (int i = t; i < 16 * BINSZ; i += 1024) {
        const int r = i & 127;
        hist[i] += rowStart[r] - cnt[r];
    }
    __syncthreads();
    for (int e = e0 + t; e < e1; e += 1024) {
        const unsigned u = binned[e];
        const int r = (int)(u >> 18);
        const int p = atomicAdd(&hist[(w << 7) | r], 1);  // intra-wave contention only
        srcSorted[e0 + p] = (int)(u & 0x3FFFFu);
    }
    if (bin == 0 && t == 0) rowptr[NNODES] = NEDGE;
}

// ---------------- per-layer compute (unfused) ----------------

// h[i][j] = sum_k act(x[i][k]) * W[j][k] + b[j]; H stored fp16
template <int MODE>
__global__ void linear_kernel(const float* __restrict__ xa, const float* __restrict__ xb,
                              const float* __restrict__ W, const float* __restrict__ b,
                              __half* __restrict__ H) {
    __shared__ float Wt[D * D];
    __shared__ float bs[D];
    const int tid = threadIdx.x;
    for (int t = tid; t < D * D; t += blockDim.x) {
        int j = t / D, k = t % D;
        Wt[k * D + j] = W[j * D + k];
    }
    if (tid < D) bs[tid] = b[tid];
    __syncthreads();

    const int row = blockIdx.x * 8 + (tid >> 5);
    const int j = tid & 31;

    float xv;
    if (MODE == 0) {
        xv = (row < N_ROWS) ? xa[row * D + j] : xb[(row - N_ROWS) * D + j];
    } else {
        xv = fmaxf(xa[row * D + j], 0.0f);
    }

    float acc = bs[j];
#pragma unroll
    for (int k = 0; k < D; ++k) {
        float a = __shfl(xv, k, D);
        acc = fmaf(a, Wt[k * D + j], acc);
    }
    H[row * D + j] = __float2half(acc);
}

// 16 lanes per dst row, half2 per lane: half the loads/addr-VALU, 2x lines in flight.
template <bool RELU>
__global__ void agg_csr(const int* __restrict__ rowptr, const int* __restrict__ srcSorted,
                        const __half* __restrict__ H, float* __restrict__ OUT) {
    const int tid = threadIdx.x;
    const int d = blockIdx.x * 16 + (tid >> 4);
    const int j = tid & 15;
    const unsigned int* __restrict__ H2 = (const unsigned int*)H;  // 16 uints per row

    int e = rowptr[d];
    const int eEnd = rowptr[d + 1];
    float2 acc = __half22float2(((const __half2*)H)[d * 16 + j]);  // self-loop
    for (; e + 7 < eEnd; e += 8) {
        int s[8];
#pragma unroll
        for (int k = 0; k < 8; ++k) s[k] = srcSorted[e + k];
        unsigned int v[8];
#pragma unroll
        for (int k = 0; k < 8; ++k) v[k] = H2[s[k] * 16 + j];
#pragma unroll
        for (int k = 0; k < 8; ++k) {
            const float2 f = __half22float2(*(const __half2*)&v[k]);
            acc.x += f.x;
            acc.y += f.y;
        }
    }
    for (; e < eEnd; ++e) {
        const unsigned int v = H2[srcSorted[e] * 16 + j];
        const float2 f = __half22float2(*(const __half2*)&v);
        acc.x += f.x;
        acc.y += f.y;
    }
    if (RELU) { acc.x = fmaxf(acc.x, 0.0f); acc.y = fmaxf(acc.y, 0.0f); }
    ((float2*)OUT)[d * 16 + j] = acc;
}

// ---------------- launch ----------------

extern "C" void kernel_launch(void* const* d_in, const int* in_sizes, int n_in,
                              void* d_out, int out_size, void* d_ws, size_t ws_size,
                              hipStream_t stream) {
    const float* row_embed = (const float*)d_in[0];
    const float* col_embed = (const float*)d_in[1];
    const float* W0 = (const float*)d_in[2];
    const float* b0 = (const float*)d_in[3];
    const float* W1 = (const float*)d_in[4];
    const float* b1 = (const float*)d_in[5];
    const float* W2 = (const float*)d_in[6];
    const float* b2 = (const float*)d_in[7];
    const int* ei = (const int*)d_in[8];
    const int* src = ei;
    const int* dst = ei + NEDGE;
    float* out = (float*)d_out;

    // workspace carve-up (~74 MB)
    __half* H = (__half*)d_ws;                                   // 9.6 MB
    float* B0 = (float*)(H + (size_t)NNODES * D);                // 19.2 MB
    unsigned int* binned = (unsigned int*)(B0 + (size_t)NNODES * D);  // 20 MB
    int* srcSorted = (int*)(binned + NEDGE);                     // 20 MB
    int* counts = srcSorted + NEDGE;                             // 2.4 MB
    int* bases = counts + NCOUNTS;                               // 2.4 MB
    int* partials = bases + NCOUNTS;                             // 586
    int* binPtr = partials + NSCAN;                              // NBINS+1
    int* rowptr = binPtr + (NBINS + 1);                          // NNODES+1

    const int lin_grid = NNODES / 8;   // 18750
    const int agg_grid = NNODES / 16;  // 9375

    // CSR build — atomic-free counting sort (rebuilt every call; stateless)
    count_kernel<<<NBLK, SCT, 0, stream>>>(dst, counts);
    scanA<<<NSCAN, 256, 0, stream>>>(counts, partials);
    scanB<<<1, 256, 0, stream>>>(partials);
    scanC<<<NSCAN, 256, 0, stream>>>(counts, partials, bases, binPtr);
    scatter3<<<NBLK, SCT, 0, stream>>>(src, dst, bases, binned);
    fine_sort<<<NBINS, 1024, 0, stream>>>(binPtr, binned, rowptr, srcSorted);

    // layer chain (unfused)
    linear_kernel<0><<<lin_grid, 256, 0, stream>>>(row_embed, col_embed, W0, b0, H);
    agg_csr<false><<<agg_grid, 256, 0, stream>>>(rowptr, srcSorted, H, B0);
    linear_kernel<1><<<lin_grid, 256, 0, stream>>>(B0, nullptr, W1, b1, H);
    agg_csr<false><<<agg_grid, 256, 0, stream>>>(rowptr, srcSorted, H, B0);
    linear_kernel<1><<<lin_grid, 256, 0, stream>>>(B0, nullptr, W2, b2, H);
    agg_csr<true><<<agg_grid, 256, 0, stream>>>(rowptr, srcSorted, H, out);

    (void)in_sizes; (void)n_in; (void)out_size; (void)ws_size;
}

// Round 11
// 383.336 us; speedup vs baseline: 7.2728x; 1.2848x over previous
//
#include <hip/hip_runtime.h>
#include <hip/hip_fp16.h>

#define N_ROWS 100000
#define NNODES 150000
#define D 32
#define NEDGE 5000000
#define BINSHIFT 7
#define BINSZ 128                          // nodes per bin
#define NBINS 1172                         // ceil(150000 / 128)
#define NBLK 512                           // scatter/count blocks
#define SCT 1024                           // threads per scatter/count block
#define CPB ((NEDGE + NBLK - 1) / NBLK)    // 9766 edges per block
#define NCOUNTS (NBINS * NBLK)             // 600064
#define SCAN_ITEMS 1024
#define NSCAN (NCOUNTS / SCAN_ITEMS)       // 586 (exact)

#define LIN_T 128                          // threads per linear block
#define LIN_RPB 256                        // rows per linear block (2 rows/thread)
#define LIN_GRID ((NNODES + LIN_RPB - 1) / LIN_RPB)  // 586

// ---------------- stage 1: per-(block,bin) counts matrix (no global atomics) ----------------

__global__ void count_kernel(const int* __restrict__ dst, int* __restrict__ counts) {
    __shared__ int h[4 * NBINS];
    const int t = threadIdx.x;
    const int sub = ((t >> 6) & 3) * NBINS;
    for (int b = t; b < 4 * NBINS; b += SCT) h[b] = 0;
    __syncthreads();
    const int e0 = blockIdx.x * CPB;
    const int e1 = min(e0 + CPB, NEDGE);
    for (int i = e0 + t; i < e1; i += SCT) atomicAdd(&h[sub + (dst[i] >> BINSHIFT)], 1);
    __syncthreads();
    for (int b = t; b < NBINS; b += SCT)
        counts[b * NBLK + blockIdx.x] = h[b] + h[NBINS + b] + h[2 * NBINS + b] + h[3 * NBINS + b];
}

// ---------------- stage 2: device-wide exclusive scan of counts ----------------

__global__ void scanA(const int* __restrict__ counts, int* __restrict__ partials) {
    __shared__ int s[256];
    const int t = threadIdx.x;
    const int base = blockIdx.x * SCAN_ITEMS + t * 4;
    int sum = 0;
#pragma unroll
    for (int k = 0; k < 4; ++k) sum += counts[base + k];
    s[t] = sum;
    __syncthreads();
    for (int off = 128; off > 0; off >>= 1) {
        if (t < off) s[t] += s[t + off];
        __syncthreads();
    }
    if (t == 0) partials[blockIdx.x] = s[0];
}

__global__ void scanB(int* __restrict__ partials) {
    __shared__ int s[256];
    __shared__ int carry;
    const int t = threadIdx.x;
    if (t == 0) carry = 0;
    __syncthreads();
    for (int c = 0; c < (NSCAN + 255) / 256; ++c) {
        int idx = c * 256 + t;
        int v = (idx < NSCAN) ? partials[idx] : 0;
        s[t] = v;
        __syncthreads();
        for (int off = 1; off < 256; off <<= 1) {
            int tmp = (t >= off) ? s[t - off] : 0;
            __syncthreads();
            s[t] += tmp;
            __syncthreads();
        }
        if (idx < NSCAN) partials[idx] = carry + s[t] - v;  // exclusive
        __syncthreads();
        if (t == 0) carry += s[255];
        __syncthreads();
    }
}

__global__ void scanC(const int* __restrict__ counts, const int* __restrict__ partials,
                      int* __restrict__ bases, int* __restrict__ binPtr) {
    __shared__ int s[256];
    const int t = threadIdx.x;
    const int base = blockIdx.x * SCAN_ITEMS + t * 4;
    int c[4];
    int sum = 0;
#pragma unroll
    for (int k = 0; k < 4; ++k) { c[k] = counts[base + k]; sum += c[k]; }
    s[t] = sum;
    __syncthreads();
    for (int off = 1; off < 256; off <<= 1) {
        int v = (t >= off) ? s[t - off] : 0;
        __syncthreads();
        s[t] += v;
        __syncthreads();
    }
    int run = partials[blockIdx.x] + ((t == 0) ? 0 : s[t - 1]);
#pragma unroll
    for (int k = 0; k < 4; ++k) {
        int idx = base + k;
        bases[idx] = run;
        if ((idx & (NBLK - 1)) == 0) binPtr[idx / NBLK] = run;
        run += c[k];
    }
    if (blockIdx.x == 0 && t == 0) binPtr[NBINS] = NEDGE;
}

// ---------------- stage 3: LDS-staged scatter — bin-sorted, piecewise-coalesced stores ----------------

__global__ void __launch_bounds__(SCT, 2)
scatter3(const int* __restrict__ src, const int* __restrict__ dst,
         const int* __restrict__ bases, unsigned int* __restrict__ binned) {
    __shared__ int cnt[NBINS];          // counts, then cursor
    __shared__ int lb[NBINS + 1];       // local exclusive prefix
    __shared__ int gb[NBINS];           // global base per bin for this block
    __shared__ int ssum[SCT];
    __shared__ unsigned int staged[CPB];

    const int t = threadIdx.x;
    const int e0 = blockIdx.x * CPB;
    const int e1 = min(e0 + CPB, NEDGE);
    const int n = e1 - e0;

    for (int b = t; b < NBINS; b += SCT) {
        cnt[b] = 0;
        gb[b] = bases[b * NBLK + blockIdx.x];
    }
    __syncthreads();
    for (int i = e0 + t; i < e1; i += SCT) atomicAdd(&cnt[dst[i] >> BINSHIFT], 1);
    __syncthreads();

    const int i0 = 2 * t, i1 = 2 * t + 1;
    const int c0 = (i0 < NBINS) ? cnt[i0] : 0;
    const int c1 = (i1 < NBINS) ? cnt[i1] : 0;
    ssum[t] = c0 + c1;
    __syncthreads();
    for (int off = 1; off < SCT; off <<= 1) {
        int v = (t >= off) ? ssum[t - off] : 0;
        __syncthreads();
        ssum[t] += v;
        __syncthreads();
    }
    const int excl = (t == 0) ? 0 : ssum[t - 1];
    if (i0 < NBINS) lb[i0] = excl;
    if (i1 < NBINS) lb[i1] = excl + c0;
    if (t == 0) lb[NBINS] = n;
    __syncthreads();

    for (int b = t; b < NBINS; b += SCT) cnt[b] = lb[b];
    __syncthreads();
    for (int i = e0 + t; i < e1; i += SCT) {
        const int dv = dst[i];
        const int bn = dv >> BINSHIFT;
        const int slot = atomicAdd(&cnt[bn], 1);
        staged[slot] = ((unsigned)(dv & (BINSZ - 1)) << 18) | (unsigned)src[i];
    }
    __syncthreads();

    for (int s2 = t; s2 < n; s2 += SCT) {
        int lo = 0, hi = NBINS;
        while (hi - lo > 1) {
            const int mid = (lo + hi) >> 1;
            if (lb[mid] <= s2) lo = mid; else hi = mid;
        }
        binned[gb[lo] + (s2 - lb[lo])] = staged[s2];
    }
}

// ---------------- stage 4: per-bin fine counting sort -> full CSR by dst ----------------

__global__ void fine_sort(const int* __restrict__ binPtr, const unsigned int* __restrict__ binned,
                          int* __restrict__ rowptr, int* __restrict__ srcSorted) {
    __shared__ int hist[16 * BINSZ];   // [wave][row] 8 KB
    __shared__ int cnt[BINSZ];
    __shared__ int rowStart[BINSZ];
    const int t = threadIdx.x;
    const int w = t >> 6;
    const int bin = blockIdx.x;
    const int nodeBase = bin << BINSHIFT;
    const int nNodes = min(BINSZ, NNODES - nodeBase);
    const int e0 = binPtr[bin];
    const int e1 = binPtr[bin + 1];

    for (int i = t; i < 16 * BINSZ; i += 1024) hist[i] = 0;
    __syncthreads();
    for (int e = e0 + t; e < e1; e += 1024)
        atomicAdd(&hist[(w << 7) | (binned[e] >> 18)], 1);
    __syncthreads();
    if (t < BINSZ) {
        int run = 0;
        for (int w2 = 0; w2 < 16; ++w2) {
            const int c = hist[(w2 << 7) | t];
            hist[(w2 << 7) | t] = run;
            run += c;
        }
        cnt[t] = run;
        rowStart[t] = run;
    }
    __syncthreads();
    for (int off = 1; off < BINSZ; off <<= 1) {
        int v = 0;
        if (t < BINSZ && t >= off) v = rowStart[t - off];
        __syncthreads();
        if (t < BINSZ) rowStart[t] += v;
        __syncthreads();
    }
    if (t < nNodes) rowptr[nodeBase + t] = e0 + rowStart[t] - cnt[t];
    for (int i = t; i < 16 * BINSZ; i += 1024) {
        const int r = i & 127;
        hist[i] += rowStart[r] - cnt[r];
    }
    __syncthreads();
    for (int e = e0 + t; e < e1; e += 1024) {
        const unsigned u = binned[e];
        const int r = (int)(u >> 18);
        const int p = atomicAdd(&hist[(w << 7) | r], 1);
        srcSorted[e0 + p] = (int)(u & 0x3FFFFu);
    }
    if (bin == 0 && t == 0) rowptr[NNODES] = NEDGE;
}

// ---------------- linear: row-per-thread GEMV, no shfl, no bank conflicts ----------------
// MODE 0: input = concat(row_embed, col_embed) f32, no activation.
// MODE 1: input = xa (f32 pre-relu agg), ReLU applied on read.
// H out fp16. Each thread computes 2 full rows; W read as broadcast float4 from LDS.

template <int MODE>
__global__ void __launch_bounds__(LIN_T)
linear_rows(const float* __restrict__ xa, const float* __restrict__ xb,
            const float* __restrict__ W, const float* __restrict__ b,
            __half* __restrict__ H) {
    __shared__ float xs[LIN_RPB * 33];   // 33792 B (also reused as output staging)
    __shared__ float Ws[32 * 36];        // Ws[k*36+c] = W[c][k], 16B-aligned rows
    __shared__ float bs[32];
    const int t = threadIdx.x;

    // stage W transposed + bias
    for (int i = t; i < 1024; i += LIN_T) {
        const int c = i >> 5, k = i & 31;
        Ws[k * 36 + c] = W[i];
    }
    if (t < 32) bs[t] = b[t];

    // stage input rows, coalesced (elements blk*8192 .. +8192)
    const long long ebase = (long long)blockIdx.x * (LIN_RPB * 32);
#pragma unroll 4
    for (int i = 0; i < (LIN_RPB * 32) / LIN_T; ++i) {   // 64
        const long long e = ebase + i * LIN_T + t;
        const int flat = i * LIN_T + t;
        float v = 0.0f;
        if (e < (long long)NNODES * 32) {
            if (MODE == 0) {
                v = (e < (long long)N_ROWS * 32) ? xa[e] : xb[e - (long long)N_ROWS * 32];
            } else {
                v = fmaxf(xa[e], 0.0f);  // ReLU on read
            }
        }
        xs[(flat >> 5) * 33 + (flat & 31)] = v;
    }
    __syncthreads();

    // 2 rows per thread, fully unrolled (static register indexing)
    float a0[32], a1[32];
#pragma unroll
    for (int c = 0; c < 32; ++c) { a0[c] = bs[c]; a1[c] = bs[c]; }
    const int r0 = 2 * t, r1 = 2 * t + 1;
#pragma unroll
    for (int k = 0; k < 32; ++k) {
        const float x0 = xs[r0 * 33 + k];
        const float x1 = xs[r1 * 33 + k];
        const float4* wr = (const float4*)&Ws[k * 36];
#pragma unroll
        for (int q = 0; q < 8; ++q) {
            const float4 w = wr[q];  // broadcast read: same address across lanes
            a0[4 * q + 0] = fmaf(x0, w.x, a0[4 * q + 0]);
            a0[4 * q + 1] = fmaf(x0, w.y, a0[4 * q + 1]);
            a0[4 * q + 2] = fmaf(x0, w.z, a0[4 * q + 2]);
            a0[4 * q + 3] = fmaf(x0, w.w, a0[4 * q + 3]);
            a1[4 * q + 0] = fmaf(x1, w.x, a1[4 * q + 0]);
            a1[4 * q + 1] = fmaf(x1, w.y, a1[4 * q + 1]);
            a1[4 * q + 2] = fmaf(x1, w.z, a1[4 * q + 2]);
            a1[4 * q + 3] = fmaf(x1, w.w, a1[4 * q + 3]);
        }
    }
    __syncthreads();  // xs about to be reused as output staging

    // pack half2 into LDS staging [LIN_RPB][17] uints, then coalesced store
    unsigned* os = (unsigned*)xs;
#pragma unroll
    for (int p = 0; p < 16; ++p) {
        __half2 h0 = __floats2half2_rn(a0[2 * p], a0[2 * p + 1]);
        __half2 h1 = __floats2half2_rn(a1[2 * p], a1[2 * p + 1]);
        os[r0 * 17 + p] = *(unsigned*)&h0;
        os[r1 * 17 + p] = *(unsigned*)&h1;
    }
    __syncthreads();
    unsigned* H2 = (unsigned*)H;
    const long long obase = (long long)blockIdx.x * (LIN_RPB * 16);
#pragma unroll 4
    for (int i = 0; i < (LIN_RPB * 16) / LIN_T; ++i) {   // 32
        const long long o = obase + i * LIN_T + t;
        const int flat = i * LIN_T + t;
        if (o < (long long)NNODES * 16)
            H2[o] = os[(flat >> 4) * 17 + (flat & 15)];
    }
}

// ---------------- aggregation: 16 lanes per dst row, half2 per lane ----------------

template <bool RELU>
__global__ void agg_csr(const int* __restrict__ rowptr, const int* __restrict__ srcSorted,
                        const __half* __restrict__ H, float* __restrict__ OUT) {
    const int tid = threadIdx.x;
    const int d = blockIdx.x * 16 + (tid >> 4);
    const int j = tid & 15;
    const unsigned int* __restrict__ H2 = (const unsigned int*)H;  // 16 uints per row

    int e = rowptr[d];
    const int eEnd = rowptr[d + 1];
    float2 acc = __half22float2(((const __half2*)H)[d * 16 + j]);  // self-loop
    for (; e + 7 < eEnd; e += 8) {
        int s[8];
#pragma unroll
        for (int k = 0; k < 8; ++k) s[k] = srcSorted[e + k];
        unsigned int v[8];
#pragma unroll
        for (int k = 0; k < 8; ++k) v[k] = H2[s[k] * 16 + j];
#pragma unroll
        for (int k = 0; k < 8; ++k) {
            const float2 f = __half22float2(*(const __half2*)&v[k]);
            acc.x += f.x;
            acc.y += f.y;
        }
    }
    for (; e < eEnd; ++e) {
        const unsigned int v = H2[srcSorted[e] * 16 + j];
        const float2 f = __half22float2(*(const __half2*)&v);
        acc.x += f.x;
        acc.y += f.y;
    }
    if (RELU) { acc.x = fmaxf(acc.x, 0.0f); acc.y = fmaxf(acc.y, 0.0f); }
    ((float2*)OUT)[d * 16 + j] = acc;
}

// ---------------- launch ----------------

extern "C" void kernel_launch(void* const* d_in, const int* in_sizes, int n_in,
                              void* d_out, int out_size, void* d_ws, size_t ws_size,
                              hipStream_t stream) {
    const float* row_embed = (const float*)d_in[0];
    const float* col_embed = (const float*)d_in[1];
    const float* W0 = (const float*)d_in[2];
    const float* b0 = (const float*)d_in[3];
    const float* W1 = (const float*)d_in[4];
    const float* b1 = (const float*)d_in[5];
    const float* W2 = (const float*)d_in[6];
    const float* b2 = (const float*)d_in[7];
    const int* ei = (const int*)d_in[8];
    const int* src = ei;
    const int* dst = ei + NEDGE;
    float* out = (float*)d_out;

    // workspace carve-up (~74 MB)
    __half* H = (__half*)d_ws;                                   // 9.6 MB
    float* B0 = (float*)(H + (size_t)NNODES * D);                // 19.2 MB
    unsigned int* binned = (unsigned int*)(B0 + (size_t)NNODES * D);  // 20 MB
    int* srcSorted = (int*)(binned + NEDGE);                     // 20 MB
    int* counts = srcSorted + NEDGE;                             // 2.4 MB
    int* bases = counts + NCOUNTS;                               // 2.4 MB
    int* partials = bases + NCOUNTS;                             // 586
    int* binPtr = partials + NSCAN;                              // NBINS+1
    int* rowptr = binPtr + (NBINS + 1);                          // NNODES+1

    const int agg_grid = NNODES / 16;  // 9375

    // CSR build — atomic-free counting sort (rebuilt every call; stateless)
    count_kernel<<<NBLK, SCT, 0, stream>>>(dst, counts);
    scanA<<<NSCAN, 256, 0, stream>>>(counts, partials);
    scanB<<<1, 256, 0, stream>>>(partials);
    scanC<<<NSCAN, 256, 0, stream>>>(counts, partials, bases, binPtr);
    scatter3<<<NBLK, SCT, 0, stream>>>(src, dst, bases, binned);
    fine_sort<<<NBINS, 1024, 0, stream>>>(binPtr, binned, rowptr, srcSorted);

    // layer chain (unfused; linears are row-per-thread GEMV)
    linear_rows<0><<<LIN_GRID, LIN_T, 0, stream>>>(row_embed, col_embed, W0, b0, H);
    agg_csr<false><<<agg_grid, 256, 0, stream>>>(rowptr, srcSorted, H, B0);
    linear_rows<1><<<LIN_GRID, LIN_T, 0, stream>>>(B0, nullptr, W1, b1, H);
    agg_csr<false><<<agg_grid, 256, 0, stream>>>(rowptr, srcSorted, H, B0);
    linear_rows<1><<<LIN_GRID, LIN_T, 0, stream>>>(B0, nullptr, W2, b2, H);
    agg_csr<true><<<agg_grid, 256, 0, stream>>>(rowptr, srcSorted, H, out);

    (void)in_sizes; (void)n_in; (void)out_size; (void)ws_size;
}